// Round 5
// baseline (289.493 us; speedup 1.0000x reference)
//
#include <hip/hip_runtime.h>
#include <math.h>

#define B 4
#define SEQ 8192
#define DIM 1024
#define HEADS 8
#define NCHUNK 256
#define LOG_NCHUNK 8
#define CLEN (SEQ / NCHUNK)      // 32 rows per chunk
#define LN_EPS 1e-5f

typedef float vf4 __attribute__((ext_vector_type(4)));

// ---------------------------------------------------------------------------
// Pass 1: fused LayerNorm + local EMA + local OUTPUT, wave-per-chunk.
// Computes out_loc = y_loc + u*D entirely in registers and writes it with
// REGULAR stores (stays dirty in the 256 MB L3 for pass 3's re-read).
// x is read exactly once in the whole pipeline now -> NONTEMPORAL loads so
// the 134 MB of x never pollutes L3. No stats buffer anymore.
// LN reduction is a pure 6-level __shfl_xor: no LDS, no barriers.
// ---------------------------------------------------------------------------
__global__ void __launch_bounds__(256) pass1_kernel(
        const float* __restrict__ x,
        const float* __restrict__ gamma,
        const float* __restrict__ beta,
        const float* __restrict__ alphas,
        const float* __restrict__ paramD,
        float4* __restrict__ carry,
        float4* __restrict__ out) {
    const int t     = threadIdx.x;
    const int wave  = t >> 6;
    const int lane  = t & 63;
    const int gcid  = blockIdx.x * 4 + wave;       // chunk id in [0, B*NCHUNK)
    const int chunk = gcid & (NCHUNK - 1);
    const int b     = gcid >> LOG_NCHUNK;

    // lane's channels: c_j = lane*4 + j*256  ->  head h_j = (lane>>5) + 2*j
    float a[4], dec[4];
    float4 g[4], be[4], D[4];
#pragma unroll
    for (int j = 0; j < 4; ++j) {
        const int h = (lane >> 5) + 2 * j;
        a[j]   = 1.f / (1.f + expf(-alphas[h]));
        dec[j] = 1.f - a[j];
        g[j]   = *(const float4*)(gamma  + lane * 4 + j * 256);
        be[j]  = *(const float4*)(beta   + lane * 4 + j * 256);
        D[j]   = *(const float4*)(paramD + lane * 4 + j * 256);
    }

    const int rowbase = b * SEQ + chunk * CLEN;
    const vf4*    xp = (const vf4*)x + (long)rowbase * (DIM / 4) + lane;
    float4*       op = (float4*)out  + (long)rowbase * (DIM / 4) + lane;

    float4 y[4];
#pragma unroll
    for (int j = 0; j < 4; ++j) y[j] = make_float4(0.f, 0.f, 0.f, 0.f);

    vf4 xv[4];
#pragma unroll
    for (int j = 0; j < 4; ++j)
        xv[j] = __builtin_nontemporal_load(xp + j * 64);

    for (int i = 0; i < CLEN; ++i) {
        // prefetch next row (nontemporal); no barriers -> stays in flight
        const int ip = (i + 1 < CLEN) ? i + 1 : i;
        vf4 xn[4];
#pragma unroll
        for (int j = 0; j < 4; ++j)
            xn[j] = __builtin_nontemporal_load(xp + ip * 256 + j * 64);

        float s = 0.f, ss = 0.f;
#pragma unroll
        for (int j = 0; j < 4; ++j) {
            s  += xv[j].x + xv[j].y + xv[j].z + xv[j].w;
            ss += xv[j].x * xv[j].x + xv[j].y * xv[j].y
                + xv[j].z * xv[j].z + xv[j].w * xv[j].w;
        }
#pragma unroll
        for (int off = 32; off > 0; off >>= 1) {
            s  += __shfl_xor(s, off);
            ss += __shfl_xor(ss, off);
        }
        const float mean = s * (1.f / DIM);
        const float var  = ss * (1.f / DIM) - mean * mean;
        const float rstd = rsqrtf(var + LN_EPS);

#pragma unroll
        for (int j = 0; j < 4; ++j) {
            float4 u, o;
            u.x = (xv[j].x - mean) * rstd * g[j].x + be[j].x;
            u.y = (xv[j].y - mean) * rstd * g[j].y + be[j].y;
            u.z = (xv[j].z - mean) * rstd * g[j].z + be[j].z;
            u.w = (xv[j].w - mean) * rstd * g[j].w + be[j].w;
            y[j].x = dec[j] * y[j].x + a[j] * u.x;
            y[j].y = dec[j] * y[j].y + a[j] * u.y;
            y[j].z = dec[j] * y[j].z + a[j] * u.z;
            y[j].w = dec[j] * y[j].w + a[j] * u.w;
            o.x = y[j].x + u.x * D[j].x;
            o.y = y[j].y + u.y * D[j].y;
            o.z = y[j].z + u.z * D[j].z;
            o.w = y[j].w + u.w * D[j].w;
            op[i * 256 + j * 64] = o;              // regular store: keep in L3
            xv[j] = xn[j];
        }
    }
#pragma unroll
    for (int j = 0; j < 4; ++j)
        carry[(long)gcid * (DIM / 4) + lane + j * 64] = y[j];
}

// ---------------------------------------------------------------------------
// Pass 2 (tiny): serial scan of chunk carries per channel, IN-PLACE.
// (unchanged from the measured-best version)
// ---------------------------------------------------------------------------
__global__ void __launch_bounds__(64) carry_scan_kernel(
        const float* __restrict__ alphas,
        float* __restrict__ carry) {
    const int tid = blockIdx.x * 64 + threadIdx.x;   // [0, B*DIM)
    const int c   = tid & (DIM - 1);
    const int b   = tid >> 10;
    const int h   = c >> 7;

    const float a = 1.f / (1.f + expf(-alphas[h]));
    const float r = 1.f - a;
    float rn = r;                                    // r^32 = r squared 5 times
#pragma unroll
    for (int q = 0; q < 5; ++q) rn = rn * rn;        // CLEN == 32

    float* cp = carry + (long)b * NCHUNK * DIM + c;

    float Y = 0.f;
#pragma unroll 16
    for (int k = 0; k < NCHUNK; ++k) {
        const float loc = cp[(long)k * DIM];
        cp[(long)k * DIM] = Y;                       // exclusive prefix
        Y = rn * Y + loc;
    }
}

// ---------------------------------------------------------------------------
// Pass 3: pure streaming correction. out[i] += dec^(i+1) * Y0.
// No x re-read, no LN recompute, no serial memory chain: the only recurrence
// is cdec[j] *= dec[j] (4 VALU ops/row). Reads hit the L3-resident out_loc
// written by pass 1; final values leave via nontemporal stores.
// ---------------------------------------------------------------------------
__global__ void __launch_bounds__(256) pass3_kernel(
        const float* __restrict__ alphas,
        const float4* __restrict__ excl,
        float4* __restrict__ out) {
    const int t     = threadIdx.x;
    const int wave  = t >> 6;
    const int lane  = t & 63;
    const int gcid  = blockIdx.x * 4 + wave;
    const int chunk = gcid & (NCHUNK - 1);
    const int b     = gcid >> LOG_NCHUNK;

    float dec[4], cdec[4];
    float4 Y0[4];
#pragma unroll
    for (int j = 0; j < 4; ++j) {
        const int h = (lane >> 5) + 2 * j;
        const float a = 1.f / (1.f + expf(-alphas[h]));
        dec[j]  = 1.f - a;
        cdec[j] = dec[j];                            // dec^(i+1) at i=0
        Y0[j]   = excl[(long)gcid * (DIM / 4) + lane + j * 64];
    }

    const int rowbase = b * SEQ + chunk * CLEN;
    float4* op = (float4*)out + (long)rowbase * (DIM / 4) + lane;

    float4 ov[4];
#pragma unroll
    for (int j = 0; j < 4; ++j) ov[j] = op[j * 64];

    for (int i = 0; i < CLEN; ++i) {
        const int ip = (i + 1 < CLEN) ? i + 1 : i;
        float4 on[4];
#pragma unroll
        for (int j = 0; j < 4; ++j) on[j] = op[ip * 256 + j * 64];

#pragma unroll
        for (int j = 0; j < 4; ++j) {
            vf4 vo = { ov[j].x + cdec[j] * Y0[j].x,
                       ov[j].y + cdec[j] * Y0[j].y,
                       ov[j].z + cdec[j] * Y0[j].z,
                       ov[j].w + cdec[j] * Y0[j].w };
            __builtin_nontemporal_store(vo, (vf4*)(op + i * 256 + j * 64));
            cdec[j] *= dec[j];
            ov[j] = on[j];
        }
    }
}

// ---------------------------------------------------------------------------
extern "C" void kernel_launch(void* const* d_in, const int* in_sizes, int n_in,
                              void* d_out, int out_size, void* d_ws, size_t ws_size,
                              hipStream_t stream) {
    const float* x      = (const float*)d_in[0];
    const float* gamma  = (const float*)d_in[1];
    const float* beta   = (const float*)d_in[2];
    const float* alphas = (const float*)d_in[3];
    const float* paramD = (const float*)d_in[4];
    float* out = (float*)d_out;

    float* carry = (float*)d_ws;                     // 4 MB, scanned in place

    pass1_kernel<<<B * NCHUNK / 4, 256, 0, stream>>>(
        x, gamma, beta, alphas, paramD, (float4*)carry, (float4*)out);
    carry_scan_kernel<<<B * DIM / 64, 64, 0, stream>>>(alphas, carry);
    pass3_kernel<<<B * NCHUNK / 4, 256, 0, stream>>>(
        alphas, (const float4*)carry, (float4*)out);
}